// Round 9
// baseline (53.930 us; speedup 1.0000x reference)
//
#include <hip/hip_runtime.h>
#include <hip/hip_bf16.h>

typedef __attribute__((ext_vector_type(8))) short short8;
typedef __attribute__((ext_vector_type(4))) float floatx4;
typedef __attribute__((ext_vector_type(2))) float floatx2;

static __device__ __forceinline__ short f2bf(float f) {
    union { float f; unsigned u; } v; v.f = f;
    unsigned r = v.u + 0x7fffu + ((v.u >> 16) & 1u);
    return (short)(r >> 16);
}
static __device__ __forceinline__ float bf2f(short s) {
    union { unsigned u; float f; } v; v.u = ((unsigned)(unsigned short)s) << 16;
    return v.f;
}

#define C_CTX 10
#define D_EMB 128
#define E_DIM 256

// Column permutation on h's contraction dim: stored position pc <-> original col
//   pc  = w*64 + c*4 + ni   (w = pc>>6, c = (pc>>2)&15, ni = pc&3)
//   oc  = w*64 + ni*16 + c
// Applied consistently to: G (fp8), Tt (bf16), and B2f's k index. Outputs unaffected.

// ---- prep: bf16 MFMA B-fragments for M1 (cols 0:128 of Mw), M2 (cols 128:256), U|W ----
__global__ void prep_main(const float* __restrict__ Mw, const float* __restrict__ Uw,
                          const float* __restrict__ Ww, short* __restrict__ M1f,
                          short* __restrict__ M2f, short* __restrict__ B2f)
{
    int u = blockIdx.x * 256 + threadIdx.x;   // 0..16383
    if (u < 8192) {
        int f = u & 4095;
        int l = f & 63, kc = (f >> 6) & 3, grp = f >> 8;     // grp 0..15
        int e = grp * 16 + (l & 15);
        int k = kc * 32 + (l >> 4) * 8 + ((u < 4096) ? 0 : 128);
        const float* src = Mw + (size_t)e * E_DIM + k;
        float4 x = *(const float4*)src;
        float4 y = *(const float4*)(src + 4);
        short8 o;
        o[0]=f2bf(x.x); o[1]=f2bf(x.y); o[2]=f2bf(x.z); o[3]=f2bf(x.w);
        o[4]=f2bf(y.x); o[5]=f2bf(y.y); o[6]=f2bf(y.z); o[7]=f2bf(y.w);
        *(short8*)(((u < 4096) ? M1f : M2f) + (size_t)f * 8) = o;
    } else {
        int f = u - 8192;
        int l = f & 63, ni = (f >> 6) & 3, kc = (f >> 8) & 7, w = f >> 11;
        int e = w * 64 + ni * 16 + (l & 15);
        const float* src = (e < 128) ? (Uw + (size_t)e * E_DIM)
                                     : (Ww + (size_t)(e - 128) * E_DIM);
        short8 o;
        #pragma unroll
        for (int i = 0; i < 8; ++i) {
            int pk = kc * 32 + (l >> 4) * 8 + i;                       // permuted k
            int ok = (pk >> 6) * 64 + (pk & 3) * 16 + ((pk >> 2) & 15); // original k
            o[i] = f2bf(src[ok]);
        }
        *(short8*)(B2f + (size_t)f * 8) = o;
    }
}

// ---- k_gt2: blocks [0,NG): G8 = fp8(R@M1^T), permuted cols. blocks [NG,..): Ttb = bf16(R[tgt]@M2^T + Mb), permuted cols.
// 64 rows/block; direct packed stores (no LDS transpose).
__global__ __launch_bounds__(256, 4)
void k_gt2(const float* __restrict__ R, const short* __restrict__ M1f,
           const short* __restrict__ M2f, const float* __restrict__ Mb,
           const int* __restrict__ tgt, unsigned char* __restrict__ G8,
           short* __restrict__ Ttb, int V, int NG)
{
    __shared__ __align__(16) short buf[1024 * 8];   // 16 KB A-frag stage
    __shared__ int tids[64];
    const int t = threadIdx.x, w = t >> 6, l = t & 63;
    const bool isG = (int)blockIdx.x < NG;
    const int r0 = (isG ? blockIdx.x : (blockIdx.x - NG)) * 64;

    if (!isG && t < 64) tids[t] = tgt[r0 + t];
    if (!isG) __syncthreads();

    // stage A fragments (frag-linear, conflict-free): 1024 short8 units
    #pragma unroll
    for (int i = 0; i < 4; ++i) {
        int fa = t + i * 256;
        int li = fa & 63, frag = fa >> 6;     // 0..15
        int kc = frag >> 2, mi = frag & 3;
        int r = mi * 16 + (li & 15);
        int k = kc * 32 + (li >> 4) * 8;
        int gr;
        if (isG) { gr = r0 + r; if (gr >= V) gr = V - 1; }
        else     { gr = tids[r]; }
        const float* s = R + (size_t)gr * D_EMB + k;
        float4 x = *(const float4*)s;
        float4 y = *(const float4*)(s + 4);
        short8 v;
        v[0]=f2bf(x.x); v[1]=f2bf(x.y); v[2]=f2bf(x.z); v[3]=f2bf(x.w);
        v[4]=f2bf(y.x); v[5]=f2bf(y.y); v[6]=f2bf(y.z); v[7]=f2bf(y.w);
        *(short8*)&buf[fa * 8] = v;
    }
    __syncthreads();

    const short* Bf = isG ? M1f : M2f;
    floatx4 acc[4][4];
    #pragma unroll
    for (int mi = 0; mi < 4; ++mi)
        #pragma unroll
        for (int ni = 0; ni < 4; ++ni)
            acc[mi][ni] = (floatx4){0.f, 0.f, 0.f, 0.f};

    #pragma unroll
    for (int kc = 0; kc < 4; ++kc) {
        short8 afr[4], bfr[4];
        #pragma unroll
        for (int mi = 0; mi < 4; ++mi)
            afr[mi] = *(const short8*)&buf[((kc * 4 + mi) * 64 + l) * 8];
        #pragma unroll
        for (int ni = 0; ni < 4; ++ni)
            bfr[ni] = *(const short8*)(Bf + (((size_t)(w * 4 + ni) * 4 + kc) * 64 + l) * 8);
        #pragma unroll
        for (int mi = 0; mi < 4; ++mi)
            #pragma unroll
            for (int ni = 0; ni < 4; ++ni)
                acc[mi][ni] = __builtin_amdgcn_mfma_f32_16x16x32_bf16(afr[mi], bfr[ni], acc[mi][ni], 0, 0, 0);
    }

    // epilogue: per (mi,j) pack the 4 ni-values and store at permuted cols
    const int pcb = w * 64 + (l & 15) * 4;   // permuted col base for this lane
    if (isG) {
        #pragma unroll
        for (int mi = 0; mi < 4; ++mi)
            #pragma unroll
            for (int j = 0; j < 4; ++j) {
                int row = r0 + mi * 16 + (l >> 4) * 4 + j;
                if (row < V) {
                    int u = __builtin_amdgcn_cvt_pk_fp8_f32(acc[mi][0][j], acc[mi][1][j], 0, false);
                    u = __builtin_amdgcn_cvt_pk_fp8_f32(acc[mi][2][j], acc[mi][3][j], u, true);
                    *(int*)(G8 + (size_t)row * 256 + pcb) = u;
                }
            }
    } else {
        float mb[4];
        #pragma unroll
        for (int ni = 0; ni < 4; ++ni) mb[ni] = Mb[w * 64 + ni * 16 + (l & 15)];
        #pragma unroll
        for (int mi = 0; mi < 4; ++mi)
            #pragma unroll
            for (int j = 0; j < 4; ++j) {
                int row = r0 + mi * 16 + (l >> 4) * 4 + j;
                unsigned u0 = ((unsigned)(unsigned short)f2bf(acc[mi][1][j] + mb[1]) << 16)
                            |  (unsigned)(unsigned short)f2bf(acc[mi][0][j] + mb[0]);
                unsigned u1 = ((unsigned)(unsigned short)f2bf(acc[mi][3][j] + mb[3]) << 16)
                            |  (unsigned)(unsigned short)f2bf(acc[mi][2][j] + mb[2]);
                uint2 uv; uv.x = u0; uv.y = u1;
                *(uint2*)(Ttb + (size_t)row * 256 + pcb) = uv;
            }
    }
}

// ---- k_hh: 16 b's/block. h = sum_c relu(G8[ctx] + Ttb) (permuted cols) -> LDS frags -> heads GEMM
// All 22 gather loads batch-issued into registers before any accumulation
// (forces the compiler to keep them in flight -> one latency exposure).
__global__ __launch_bounds__(256, 4)
void k_hh(const int* __restrict__ ctx, const unsigned char* __restrict__ G8,
          const short* __restrict__ Ttb, const short* __restrict__ B2f,
          const float* __restrict__ Ub, const float* __restrict__ Wb,
          float* __restrict__ out, int Bsz)
{
    __shared__ __align__(16) short hfr[8 * 64 * 8];   // 8 KB
    __shared__ int ids[16 * C_CTX];
    const int t = threadIdx.x, w = t >> 6, l = t & 63;
    const int b0 = blockIdx.x * 16;

    if (t < 16 * C_CTX) ids[t] = ctx[(size_t)b0 * C_CTX + t];
    __syncthreads();

    const int hw = l >> 5;               // half-wave
    const int i5 = l & 31;
    const int kcc = i5 & 7, sub = i5 >> 3;
    const int c8 = kcc * 32 + sub * 8;   // permuted col base; 32 lanes cover the row
    const int bl0 = w * 2 + hw;          // local row 0..7
    const int bl1 = bl0 + 8;             // local row 8..15

    // ---- batch-issue ALL loads ----
    short8 tr0 = *(const short8*)(Ttb + (size_t)(b0 + bl0) * E_DIM + c8);
    short8 tr1 = *(const short8*)(Ttb + (size_t)(b0 + bl1) * E_DIM + c8);
    uint2 g0[C_CTX], g1[C_CTX];
    #pragma unroll
    for (int c = 0; c < C_CTX; ++c)
        g0[c] = *(const uint2*)(G8 + (size_t)ids[bl0 * C_CTX + c] * E_DIM + c8);
    #pragma unroll
    for (int c = 0; c < C_CTX; ++c)
        g1[c] = *(const uint2*)(G8 + (size_t)ids[bl1 * C_CTX + c] * E_DIM + c8);

    // ---- accumulate row bl0 ----
    {
        float tv[8], acc[8];
        #pragma unroll
        for (int j = 0; j < 8; ++j) { tv[j] = bf2f(tr0[j]); acc[j] = 0.f; }
        #pragma unroll
        for (int c = 0; c < C_CTX; ++c) {
            floatx2 d01 = __builtin_amdgcn_cvt_pk_f32_fp8((int)g0[c].x, false);
            floatx2 d23 = __builtin_amdgcn_cvt_pk_f32_fp8((int)g0[c].x, true);
            floatx2 d45 = __builtin_amdgcn_cvt_pk_f32_fp8((int)g0[c].y, false);
            floatx2 d67 = __builtin_amdgcn_cvt_pk_f32_fp8((int)g0[c].y, true);
            acc[0] += fmaxf(d01[0] + tv[0], 0.f);
            acc[1] += fmaxf(d01[1] + tv[1], 0.f);
            acc[2] += fmaxf(d23[0] + tv[2], 0.f);
            acc[3] += fmaxf(d23[1] + tv[3], 0.f);
            acc[4] += fmaxf(d45[0] + tv[4], 0.f);
            acc[5] += fmaxf(d45[1] + tv[5], 0.f);
            acc[6] += fmaxf(d67[0] + tv[6], 0.f);
            acc[7] += fmaxf(d67[1] + tv[7], 0.f);
        }
        int sp = (sub * 16 + bl0) ^ kcc;
        short8 o;
        #pragma unroll
        for (int j = 0; j < 8; ++j) o[j] = f2bf(acc[j]);
        *(short8*)&hfr[(kcc * 64 + sp) * 8] = o;
    }
    // ---- accumulate row bl1 ----
    {
        float tv[8], acc[8];
        #pragma unroll
        for (int j = 0; j < 8; ++j) { tv[j] = bf2f(tr1[j]); acc[j] = 0.f; }
        #pragma unroll
        for (int c = 0; c < C_CTX; ++c) {
            floatx2 d01 = __builtin_amdgcn_cvt_pk_f32_fp8((int)g1[c].x, false);
            floatx2 d23 = __builtin_amdgcn_cvt_pk_f32_fp8((int)g1[c].x, true);
            floatx2 d45 = __builtin_amdgcn_cvt_pk_f32_fp8((int)g1[c].y, false);
            floatx2 d67 = __builtin_amdgcn_cvt_pk_f32_fp8((int)g1[c].y, true);
            acc[0] += fmaxf(d01[0] + tv[0], 0.f);
            acc[1] += fmaxf(d01[1] + tv[1], 0.f);
            acc[2] += fmaxf(d23[0] + tv[2], 0.f);
            acc[3] += fmaxf(d23[1] + tv[3], 0.f);
            acc[4] += fmaxf(d45[0] + tv[4], 0.f);
            acc[5] += fmaxf(d45[1] + tv[5], 0.f);
            acc[6] += fmaxf(d67[0] + tv[6], 0.f);
            acc[7] += fmaxf(d67[1] + tv[7], 0.f);
        }
        int sp = (sub * 16 + bl1) ^ kcc;
        short8 o;
        #pragma unroll
        for (int j = 0; j < 8; ++j) o[j] = f2bf(acc[j]);
        *(short8*)&hfr[(kcc * 64 + sp) * 8] = o;
    }
    __syncthreads();

    // heads GEMM: 16 rows x 256 cols x K=256 (K in permuted order, matching B2f)
    floatx4 acc2[4];
    #pragma unroll
    for (int ni = 0; ni < 4; ++ni)
        acc2[ni] = (floatx4){0.f, 0.f, 0.f, 0.f};

    #pragma unroll
    for (int kc = 0; kc < 8; ++kc) {
        short8 afr = *(const short8*)&hfr[(kc * 64 + (l ^ kc)) * 8];
        short8 bfr[4];
        #pragma unroll
        for (int ni = 0; ni < 4; ++ni)
            bfr[ni] = *(const short8*)(B2f + ((((size_t)w * 8 + kc) * 4 + ni) * 64 + l) * 8);
        #pragma unroll
        for (int ni = 0; ni < 4; ++ni)
            acc2[ni] = __builtin_amdgcn_mfma_f32_16x16x32_bf16(afr, bfr[ni], acc2[ni], 0, 0, 0);
    }

    #pragma unroll
    for (int ni = 0; ni < 4; ++ni) {
        int col = w * 64 + ni * 16 + (l & 15);
        #pragma unroll
        for (int j = 0; j < 4; ++j) {
            int rr = (l >> 4) * 4 + j;   // 0..15
            int r = b0 + rr;
            float v = acc2[ni][j];
            if (col < 128) {
                out[(size_t)r * 128 + col] = v + Ub[col];
            } else {
                float xx = v + Wb[col - 128];
                float sp = fmaxf(xx, 0.f) + log1pf(expf(-fabsf(xx)));
                out[(size_t)Bsz * 128 + (size_t)r * 128 + (col - 128)] = sp;
            }
        }
    }
}

// ==================== launch ====================
extern "C" void kernel_launch(void* const* d_in, const int* in_sizes, int n_in,
                              void* d_out, int out_size, void* d_ws, size_t ws_size,
                              hipStream_t stream)
{
    const int*   tgt = (const int*)d_in[0];
    const int*   ctx = (const int*)d_in[1];
    const float* R   = (const float*)d_in[2];
    const float* Mw  = (const float*)d_in[3];
    const float* Mb  = (const float*)d_in[4];
    const float* Uw  = (const float*)d_in[5];
    const float* Ub  = (const float*)d_in[6];
    const float* Ww  = (const float*)d_in[7];
    const float* Wb  = (const float*)d_in[8];
    float* out = (float*)d_out;
    const int Bsz = in_sizes[0];
    const int Vn  = in_sizes[2] / D_EMB;

    char* ws = (char*)d_ws;
    size_t offG   = 0;                               // V*256 fp8  = 25.6 MB
    size_t offT   = offG + (size_t)Vn * 256;         // B*256 bf16 = 8.4 MB
    size_t offM1f = offT + (size_t)Bsz * 512;
    size_t offM2f = offM1f + 65536;
    size_t offB2f = offM2f + 65536;

    unsigned char* G8 = (unsigned char*)(ws + offG);
    short* Ttb = (short*)(ws + offT);
    short* M1f = (short*)(ws + offM1f);
    short* M2f = (short*)(ws + offM2f);
    short* B2f = (short*)(ws + offB2f);

    const int NG = (Vn + 63) / 64;
    const int NT = Bsz / 64;

    prep_main<<<64, 256, 0, stream>>>(Mw, Uw, Ww, M1f, M2f, B2f);
    k_gt2<<<NG + NT, 256, 0, stream>>>(R, M1f, M2f, Mb, tgt, G8, Ttb, Vn, NG);
    k_hh<<<Bsz / 16, 256, 0, stream>>>(ctx, G8, Ttb, B2f, Ub, Wb, out, Bsz);
}

// Round 10
// 53.834 us; speedup vs baseline: 1.0018x; 1.0018x over previous
//
#include <hip/hip_runtime.h>
#include <hip/hip_bf16.h>

typedef __attribute__((ext_vector_type(8))) short short8;
typedef __attribute__((ext_vector_type(4))) float floatx4;
typedef __attribute__((ext_vector_type(2))) float floatx2;

static __device__ __forceinline__ short f2bf(float f) {
    union { float f; unsigned u; } v; v.f = f;
    unsigned r = v.u + 0x7fffu + ((v.u >> 16) & 1u);
    return (short)(r >> 16);
}
static __device__ __forceinline__ float bf2f(short s) {
    union { unsigned u; float f; } v; v.u = ((unsigned)(unsigned short)s) << 16;
    return v.f;
}

#define C_CTX 10
#define D_EMB 128
#define E_DIM 256

// Column permutation on h's contraction dim: stored position pc <-> original col
//   pc  = w*64 + c*4 + ni   (w = pc>>6, c = (pc>>2)&15, ni = pc&3)
//   oc  = w*64 + ni*16 + c
// Applied consistently to: G (fp8), Tt (bf16), and B2f's k index. Outputs unaffected.

// ---- prep: bf16 MFMA B-fragments for M1 (cols 0:128 of Mw), M2 (cols 128:256), U|W ----
__global__ void prep_main(const float* __restrict__ Mw, const float* __restrict__ Uw,
                          const float* __restrict__ Ww, short* __restrict__ M1f,
                          short* __restrict__ M2f, short* __restrict__ B2f)
{
    int u = blockIdx.x * 256 + threadIdx.x;   // 0..16383
    if (u < 8192) {
        int f = u & 4095;
        int l = f & 63, kc = (f >> 6) & 3, grp = f >> 8;     // grp 0..15
        int e = grp * 16 + (l & 15);
        int k = kc * 32 + (l >> 4) * 8 + ((u < 4096) ? 0 : 128);
        const float* src = Mw + (size_t)e * E_DIM + k;
        float4 x = *(const float4*)src;
        float4 y = *(const float4*)(src + 4);
        short8 o;
        o[0]=f2bf(x.x); o[1]=f2bf(x.y); o[2]=f2bf(x.z); o[3]=f2bf(x.w);
        o[4]=f2bf(y.x); o[5]=f2bf(y.y); o[6]=f2bf(y.z); o[7]=f2bf(y.w);
        *(short8*)(((u < 4096) ? M1f : M2f) + (size_t)f * 8) = o;
    } else {
        int f = u - 8192;
        int l = f & 63, ni = (f >> 6) & 3, kc = (f >> 8) & 7, w = f >> 11;
        int e = w * 64 + ni * 16 + (l & 15);
        const float* src = (e < 128) ? (Uw + (size_t)e * E_DIM)
                                     : (Ww + (size_t)(e - 128) * E_DIM);
        short8 o;
        #pragma unroll
        for (int i = 0; i < 8; ++i) {
            int pk = kc * 32 + (l >> 4) * 8 + i;                       // permuted k
            int ok = (pk >> 6) * 64 + (pk & 3) * 16 + ((pk >> 2) & 15); // original k
            o[i] = f2bf(src[ok]);
        }
        *(short8*)(B2f + (size_t)f * 8) = o;
    }
}

// ---- k_gt2: blocks [0,NG): G8 = fp8(R@M1^T), permuted cols. blocks [NG,..): Ttb = bf16(R[tgt]@M2^T + Mb), permuted cols.
// 64 rows/block; batched register staging (all 8 loads in flight), direct packed stores.
__global__ __launch_bounds__(256, 4)
void k_gt2(const float* __restrict__ R, const short* __restrict__ M1f,
           const short* __restrict__ M2f, const float* __restrict__ Mb,
           const int* __restrict__ tgt, unsigned char* __restrict__ G8,
           short* __restrict__ Ttb, int V, int NG)
{
    __shared__ __align__(16) short buf[1024 * 8];   // 16 KB A-frag stage
    __shared__ int tids[64];
    const int t = threadIdx.x, w = t >> 6, l = t & 63;
    const bool isG = (int)blockIdx.x < NG;
    const int r0 = (isG ? blockIdx.x : (blockIdx.x - NG)) * 64;

    if (!isG && t < 64) tids[t] = tgt[r0 + t];
    if (!isG) __syncthreads();

    // ---- batch-issue all 8 staging loads (no LDS writes in between -> no waitcnt serialization)
    float4 xs[4], ys[4];
    #pragma unroll
    for (int i = 0; i < 4; ++i) {
        int fa = t + i * 256;
        int li = fa & 63, frag = fa >> 6;     // 0..15
        int kc = frag >> 2, mi = frag & 3;
        int r = mi * 16 + (li & 15);
        int k = kc * 32 + (li >> 4) * 8;
        int gr;
        if (isG) { gr = r0 + r; if (gr >= V) gr = V - 1; }
        else     { gr = tids[r]; }
        const float* s = R + (size_t)gr * D_EMB + k;
        xs[i] = *(const float4*)s;
        ys[i] = *(const float4*)(s + 4);
    }
    // ---- convert + LDS write (frag-linear, conflict-free)
    #pragma unroll
    for (int i = 0; i < 4; ++i) {
        int fa = t + i * 256;
        short8 v;
        v[0]=f2bf(xs[i].x); v[1]=f2bf(xs[i].y); v[2]=f2bf(xs[i].z); v[3]=f2bf(xs[i].w);
        v[4]=f2bf(ys[i].x); v[5]=f2bf(ys[i].y); v[6]=f2bf(ys[i].z); v[7]=f2bf(ys[i].w);
        *(short8*)&buf[fa * 8] = v;
    }
    __syncthreads();

    const short* Bf = isG ? M1f : M2f;
    floatx4 acc[4][4];
    #pragma unroll
    for (int mi = 0; mi < 4; ++mi)
        #pragma unroll
        for (int ni = 0; ni < 4; ++ni)
            acc[mi][ni] = (floatx4){0.f, 0.f, 0.f, 0.f};

    #pragma unroll
    for (int kc = 0; kc < 4; ++kc) {
        short8 afr[4], bfr[4];
        #pragma unroll
        for (int mi = 0; mi < 4; ++mi)
            afr[mi] = *(const short8*)&buf[((kc * 4 + mi) * 64 + l) * 8];
        #pragma unroll
        for (int ni = 0; ni < 4; ++ni)
            bfr[ni] = *(const short8*)(Bf + (((size_t)(w * 4 + ni) * 4 + kc) * 64 + l) * 8);
        #pragma unroll
        for (int mi = 0; mi < 4; ++mi)
            #pragma unroll
            for (int ni = 0; ni < 4; ++ni)
                acc[mi][ni] = __builtin_amdgcn_mfma_f32_16x16x32_bf16(afr[mi], bfr[ni], acc[mi][ni], 0, 0, 0);
    }

    // epilogue: per (mi,j) pack the 4 ni-values and store at permuted cols
    const int pcb = w * 64 + (l & 15) * 4;   // permuted col base for this lane
    if (isG) {
        #pragma unroll
        for (int mi = 0; mi < 4; ++mi)
            #pragma unroll
            for (int j = 0; j < 4; ++j) {
                int row = r0 + mi * 16 + (l >> 4) * 4 + j;
                if (row < V) {
                    int u = __builtin_amdgcn_cvt_pk_fp8_f32(acc[mi][0][j], acc[mi][1][j], 0, false);
                    u = __builtin_amdgcn_cvt_pk_fp8_f32(acc[mi][2][j], acc[mi][3][j], u, true);
                    *(int*)(G8 + (size_t)row * 256 + pcb) = u;
                }
            }
    } else {
        float mb[4];
        #pragma unroll
        for (int ni = 0; ni < 4; ++ni) mb[ni] = Mb[w * 64 + ni * 16 + (l & 15)];
        #pragma unroll
        for (int mi = 0; mi < 4; ++mi)
            #pragma unroll
            for (int j = 0; j < 4; ++j) {
                int row = r0 + mi * 16 + (l >> 4) * 4 + j;
                unsigned u0 = ((unsigned)(unsigned short)f2bf(acc[mi][1][j] + mb[1]) << 16)
                            |  (unsigned)(unsigned short)f2bf(acc[mi][0][j] + mb[0]);
                unsigned u1 = ((unsigned)(unsigned short)f2bf(acc[mi][3][j] + mb[3]) << 16)
                            |  (unsigned)(unsigned short)f2bf(acc[mi][2][j] + mb[2]);
                uint2 uv; uv.x = u0; uv.y = u1;
                *(uint2*)(Ttb + (size_t)row * 256 + pcb) = uv;
            }
    }
}

// ---- k_hh: 16 b's/block. h = sum_c relu(G8[ctx] + Ttb) (permuted cols) -> LDS frags -> heads GEMM
__global__ __launch_bounds__(256, 4)
void k_hh(const int* __restrict__ ctx, const unsigned char* __restrict__ G8,
          const short* __restrict__ Ttb, const short* __restrict__ B2f,
          const float* __restrict__ Ub, const float* __restrict__ Wb,
          float* __restrict__ out, int Bsz)
{
    __shared__ __align__(16) short hfr[8 * 64 * 8];   // 8 KB
    __shared__ int ids[16 * C_CTX];
    const int t = threadIdx.x, w = t >> 6, l = t & 63;
    const int b0 = blockIdx.x * 16;

    if (t < 16 * C_CTX) ids[t] = ctx[(size_t)b0 * C_CTX + t];
    __syncthreads();

    const int hw = l >> 5;               // half-wave
    const int i5 = l & 31;
    const int kcc = i5 & 7, sub = i5 >> 3;
    const int c8 = kcc * 32 + sub * 8;   // permuted col base; 32 lanes cover the row
    const int bl0 = w * 2 + hw;          // local row 0..7
    const int bl1 = bl0 + 8;             // local row 8..15

    short8 tr0 = *(const short8*)(Ttb + (size_t)(b0 + bl0) * E_DIM + c8);
    short8 tr1 = *(const short8*)(Ttb + (size_t)(b0 + bl1) * E_DIM + c8);
    uint2 g0[C_CTX], g1[C_CTX];
    #pragma unroll
    for (int c = 0; c < C_CTX; ++c)
        g0[c] = *(const uint2*)(G8 + (size_t)ids[bl0 * C_CTX + c] * E_DIM + c8);
    #pragma unroll
    for (int c = 0; c < C_CTX; ++c)
        g1[c] = *(const uint2*)(G8 + (size_t)ids[bl1 * C_CTX + c] * E_DIM + c8);

    {
        float tv[8], acc[8];
        #pragma unroll
        for (int j = 0; j < 8; ++j) { tv[j] = bf2f(tr0[j]); acc[j] = 0.f; }
        #pragma unroll
        for (int c = 0; c < C_CTX; ++c) {
            floatx2 d01 = __builtin_amdgcn_cvt_pk_f32_fp8((int)g0[c].x, false);
            floatx2 d23 = __builtin_amdgcn_cvt_pk_f32_fp8((int)g0[c].x, true);
            floatx2 d45 = __builtin_amdgcn_cvt_pk_f32_fp8((int)g0[c].y, false);
            floatx2 d67 = __builtin_amdgcn_cvt_pk_f32_fp8((int)g0[c].y, true);
            acc[0] += fmaxf(d01[0] + tv[0], 0.f);
            acc[1] += fmaxf(d01[1] + tv[1], 0.f);
            acc[2] += fmaxf(d23[0] + tv[2], 0.f);
            acc[3] += fmaxf(d23[1] + tv[3], 0.f);
            acc[4] += fmaxf(d45[0] + tv[4], 0.f);
            acc[5] += fmaxf(d45[1] + tv[5], 0.f);
            acc[6] += fmaxf(d67[0] + tv[6], 0.f);
            acc[7] += fmaxf(d67[1] + tv[7], 0.f);
        }
        int sp = (sub * 16 + bl0) ^ kcc;
        short8 o;
        #pragma unroll
        for (int j = 0; j < 8; ++j) o[j] = f2bf(acc[j]);
        *(short8*)&hfr[(kcc * 64 + sp) * 8] = o;
    }
    {
        float tv[8], acc[8];
        #pragma unroll
        for (int j = 0; j < 8; ++j) { tv[j] = bf2f(tr1[j]); acc[j] = 0.f; }
        #pragma unroll
        for (int c = 0; c < C_CTX; ++c) {
            floatx2 d01 = __builtin_amdgcn_cvt_pk_f32_fp8((int)g1[c].x, false);
            floatx2 d23 = __builtin_amdgcn_cvt_pk_f32_fp8((int)g1[c].x, true);
            floatx2 d45 = __builtin_amdgcn_cvt_pk_f32_fp8((int)g1[c].y, false);
            floatx2 d67 = __builtin_amdgcn_cvt_pk_f32_fp8((int)g1[c].y, true);
            acc[0] += fmaxf(d01[0] + tv[0], 0.f);
            acc[1] += fmaxf(d01[1] + tv[1], 0.f);
            acc[2] += fmaxf(d23[0] + tv[2], 0.f);
            acc[3] += fmaxf(d23[1] + tv[3], 0.f);
            acc[4] += fmaxf(d45[0] + tv[4], 0.f);
            acc[5] += fmaxf(d45[1] + tv[5], 0.f);
            acc[6] += fmaxf(d67[0] + tv[6], 0.f);
            acc[7] += fmaxf(d67[1] + tv[7], 0.f);
        }
        int sp = (sub * 16 + bl1) ^ kcc;
        short8 o;
        #pragma unroll
        for (int j = 0; j < 8; ++j) o[j] = f2bf(acc[j]);
        *(short8*)&hfr[(kcc * 64 + sp) * 8] = o;
    }
    __syncthreads();

    // heads GEMM: 16 rows x 256 cols x K=256 (K in permuted order, matching B2f)
    floatx4 acc2[4];
    #pragma unroll
    for (int ni = 0; ni < 4; ++ni)
        acc2[ni] = (floatx4){0.f, 0.f, 0.f, 0.f};

    #pragma unroll
    for (int kc = 0; kc < 8; ++kc) {
        short8 afr = *(const short8*)&hfr[(kc * 64 + (l ^ kc)) * 8];
        short8 bfr[4];
        #pragma unroll
        for (int ni = 0; ni < 4; ++ni)
            bfr[ni] = *(const short8*)(B2f + ((((size_t)w * 8 + kc) * 4 + ni) * 64 + l) * 8);
        #pragma unroll
        for (int ni = 0; ni < 4; ++ni)
            acc2[ni] = __builtin_amdgcn_mfma_f32_16x16x32_bf16(afr, bfr[ni], acc2[ni], 0, 0, 0);
    }

    #pragma unroll
    for (int ni = 0; ni < 4; ++ni) {
        int col = w * 64 + ni * 16 + (l & 15);
        #pragma unroll
        for (int j = 0; j < 4; ++j) {
            int rr = (l >> 4) * 4 + j;   // 0..15
            int r = b0 + rr;
            float v = acc2[ni][j];
            if (col < 128) {
                out[(size_t)r * 128 + col] = v + Ub[col];
            } else {
                float xx = v + Wb[col - 128];
                float sp = fmaxf(xx, 0.f) + log1pf(expf(-fabsf(xx)));
                out[(size_t)Bsz * 128 + (size_t)r * 128 + (col - 128)] = sp;
            }
        }
    }
}

// ==================== launch ====================
extern "C" void kernel_launch(void* const* d_in, const int* in_sizes, int n_in,
                              void* d_out, int out_size, void* d_ws, size_t ws_size,
                              hipStream_t stream)
{
    const int*   tgt = (const int*)d_in[0];
    const int*   ctx = (const int*)d_in[1];
    const float* R   = (const float*)d_in[2];
    const float* Mw  = (const float*)d_in[3];
    const float* Mb  = (const float*)d_in[4];
    const float* Uw  = (const float*)d_in[5];
    const float* Ub  = (const float*)d_in[6];
    const float* Ww  = (const float*)d_in[7];
    const float* Wb  = (const float*)d_in[8];
    float* out = (float*)d_out;
    const int Bsz = in_sizes[0];
    const int Vn  = in_sizes[2] / D_EMB;

    char* ws = (char*)d_ws;
    size_t offG   = 0;                               // V*256 fp8  = 25.6 MB
    size_t offT   = offG + (size_t)Vn * 256;         // B*256 bf16 = 8.4 MB
    size_t offM1f = offT + (size_t)Bsz * 512;
    size_t offM2f = offM1f + 65536;
    size_t offB2f = offM2f + 65536;

    unsigned char* G8 = (unsigned char*)(ws + offG);
    short* Ttb = (short*)(ws + offT);
    short* M1f = (short*)(ws + offM1f);
    short* M2f = (short*)(ws + offM2f);
    short* B2f = (short*)(ws + offB2f);

    const int NG = (Vn + 63) / 64;
    const int NT = Bsz / 64;

    prep_main<<<64, 256, 0, stream>>>(Mw, Uw, Ww, M1f, M2f, B2f);
    k_gt2<<<NG + NT, 256, 0, stream>>>(R, M1f, M2f, Mb, tgt, G8, Ttb, Vn, NG);
    k_hh<<<Bsz / 16, 256, 0, stream>>>(ctx, G8, Ttb, B2f, Ub, Wb, out, Bsz);
}

// Round 11
// 53.315 us; speedup vs baseline: 1.0115x; 1.0097x over previous
//
#include <hip/hip_runtime.h>
#include <hip/hip_bf16.h>

typedef __attribute__((ext_vector_type(8))) short short8;
typedef __attribute__((ext_vector_type(4))) float floatx4;
typedef __attribute__((ext_vector_type(2))) float floatx2;

static __device__ __forceinline__ short f2bf(float f) {
    union { float f; unsigned u; } v; v.f = f;
    unsigned r = v.u + 0x7fffu + ((v.u >> 16) & 1u);
    return (short)(r >> 16);
}
static __device__ __forceinline__ float bf2f(short s) {
    union { unsigned u; float f; } v; v.u = ((unsigned)(unsigned short)s) << 16;
    return v.f;
}

#define C_CTX 10
#define D_EMB 128
#define E_DIM 256

// Column permutation on h's contraction dim: stored position pc <-> original col
//   pc  = w*64 + c*4 + ni   (w = pc>>6, c = (pc>>2)&15, ni = pc&3)
//   oc  = w*64 + ni*16 + c
// Applied consistently to: G (fp8), Tt (bf16), and B2f's k index. Outputs unaffected.

// ---- prep: bf16 MFMA B-fragments for M1 (cols 0:128 of Mw), M2 (cols 128:256), U|W ----
__global__ void prep_main(const float* __restrict__ Mw, const float* __restrict__ Uw,
                          const float* __restrict__ Ww, short* __restrict__ M1f,
                          short* __restrict__ M2f, short* __restrict__ B2f)
{
    int u = blockIdx.x * 256 + threadIdx.x;   // 0..16383
    if (u < 8192) {
        int f = u & 4095;
        int l = f & 63, kc = (f >> 6) & 3, grp = f >> 8;     // grp 0..15
        int e = grp * 16 + (l & 15);
        int k = kc * 32 + (l >> 4) * 8 + ((u < 4096) ? 0 : 128);
        const float* src = Mw + (size_t)e * E_DIM + k;
        float4 x = *(const float4*)src;
        float4 y = *(const float4*)(src + 4);
        short8 o;
        o[0]=f2bf(x.x); o[1]=f2bf(x.y); o[2]=f2bf(x.z); o[3]=f2bf(x.w);
        o[4]=f2bf(y.x); o[5]=f2bf(y.y); o[6]=f2bf(y.z); o[7]=f2bf(y.w);
        *(short8*)(((u < 4096) ? M1f : M2f) + (size_t)f * 8) = o;
    } else {
        int f = u - 8192;
        int l = f & 63, ni = (f >> 6) & 3, kc = (f >> 8) & 7, w = f >> 11;
        int e = w * 64 + ni * 16 + (l & 15);
        const float* src = (e < 128) ? (Uw + (size_t)e * E_DIM)
                                     : (Ww + (size_t)(e - 128) * E_DIM);
        short8 o;
        #pragma unroll
        for (int i = 0; i < 8; ++i) {
            int pk = kc * 32 + (l >> 4) * 8 + i;                       // permuted k
            int ok = (pk >> 6) * 64 + (pk & 3) * 16 + ((pk >> 2) & 15); // original k
            o[i] = f2bf(src[ok]);
        }
        *(short8*)(B2f + (size_t)f * 8) = o;
    }
}

struct Regs8 { float4 x[4]; float4 y[4]; };

__device__ __forceinline__ void gt_load(const float* __restrict__ R, const int* tids_h,
                                        bool isG, int r0h, int V, int t, Regs8& rg)
{
    #pragma unroll
    for (int i = 0; i < 4; ++i) {
        int fa = t + i * 256;
        int li = fa & 63, frag = fa >> 6;     // 0..15
        int kc = frag >> 2, mi = frag & 3;
        int r = mi * 16 + (li & 15);
        int k = kc * 32 + (li >> 4) * 8;
        int gr;
        if (isG) { gr = r0h + r; if (gr >= V) gr = V - 1; }
        else     { gr = tids_h[r]; }
        const float* s = R + (size_t)gr * D_EMB + k;
        rg.x[i] = *(const float4*)s;
        rg.y[i] = *(const float4*)(s + 4);
    }
}

__device__ __forceinline__ void gt_stage(short* bufh, int t, const Regs8& rg)
{
    #pragma unroll
    for (int i = 0; i < 4; ++i) {
        int fa = t + i * 256;
        short8 v;
        v[0]=f2bf(rg.x[i].x); v[1]=f2bf(rg.x[i].y); v[2]=f2bf(rg.x[i].z); v[3]=f2bf(rg.x[i].w);
        v[4]=f2bf(rg.y[i].x); v[5]=f2bf(rg.y[i].y); v[6]=f2bf(rg.y[i].z); v[7]=f2bf(rg.y[i].w);
        *(short8*)&bufh[fa * 8] = v;
    }
}

__device__ __forceinline__ void gt_compute(const short* bufh, const short* __restrict__ Bf,
                                           const float* __restrict__ Mb, bool isG,
                                           int r0h, int V, int w, int l,
                                           unsigned char* __restrict__ G8,
                                           short* __restrict__ Ttb)
{
    floatx4 acc[4][4];
    #pragma unroll
    for (int mi = 0; mi < 4; ++mi)
        #pragma unroll
        for (int ni = 0; ni < 4; ++ni)
            acc[mi][ni] = (floatx4){0.f, 0.f, 0.f, 0.f};

    #pragma unroll
    for (int kc = 0; kc < 4; ++kc) {
        short8 afr[4], bfr[4];
        #pragma unroll
        for (int mi = 0; mi < 4; ++mi)
            afr[mi] = *(const short8*)&bufh[((kc * 4 + mi) * 64 + l) * 8];
        #pragma unroll
        for (int ni = 0; ni < 4; ++ni)
            bfr[ni] = *(const short8*)(Bf + (((size_t)(w * 4 + ni) * 4 + kc) * 64 + l) * 8);
        #pragma unroll
        for (int mi = 0; mi < 4; ++mi)
            #pragma unroll
            for (int ni = 0; ni < 4; ++ni)
                acc[mi][ni] = __builtin_amdgcn_mfma_f32_16x16x32_bf16(afr[mi], bfr[ni], acc[mi][ni], 0, 0, 0);
    }

    const int pcb = w * 64 + (l & 15) * 4;   // permuted col base for this lane
    if (isG) {
        #pragma unroll
        for (int mi = 0; mi < 4; ++mi)
            #pragma unroll
            for (int j = 0; j < 4; ++j) {
                int row = r0h + mi * 16 + (l >> 4) * 4 + j;
                if (row < V) {
                    int u = __builtin_amdgcn_cvt_pk_fp8_f32(acc[mi][0][j], acc[mi][1][j], 0, false);
                    u = __builtin_amdgcn_cvt_pk_fp8_f32(acc[mi][2][j], acc[mi][3][j], u, true);
                    *(int*)(G8 + (size_t)row * 256 + pcb) = u;
                }
            }
    } else {
        float mb[4];
        #pragma unroll
        for (int ni = 0; ni < 4; ++ni) mb[ni] = Mb[w * 64 + ni * 16 + (l & 15)];
        #pragma unroll
        for (int mi = 0; mi < 4; ++mi)
            #pragma unroll
            for (int j = 0; j < 4; ++j) {
                int row = r0h + mi * 16 + (l >> 4) * 4 + j;
                unsigned u0 = ((unsigned)(unsigned short)f2bf(acc[mi][1][j] + mb[1]) << 16)
                            |  (unsigned)(unsigned short)f2bf(acc[mi][0][j] + mb[0]);
                unsigned u1 = ((unsigned)(unsigned short)f2bf(acc[mi][3][j] + mb[3]) << 16)
                            |  (unsigned)(unsigned short)f2bf(acc[mi][2][j] + mb[2]);
                uint2 uv; uv.x = u0; uv.y = u1;
                *(uint2*)(Ttb + (size_t)row * 256 + pcb) = uv;
            }
    }
}

// ---- k_gt2: 128 rows/block, two software-pipelined 64-row halves.
// blocks [0,NG): G8 = fp8(R@M1^T), permuted cols. blocks [NG,..): Ttb = bf16(R[tgt]@M2^T+Mb).
__global__ __launch_bounds__(256, 3)
void k_gt2(const float* __restrict__ R, const short* __restrict__ M1f,
           const short* __restrict__ M2f, const float* __restrict__ Mb,
           const int* __restrict__ tgt, unsigned char* __restrict__ G8,
           short* __restrict__ Ttb, int V, int NG)
{
    __shared__ __align__(16) short buf[2][1024 * 8];   // 2 x 16 KB
    __shared__ int tids[128];
    const int t = threadIdx.x, w = t >> 6, l = t & 63;
    const bool isG = (int)blockIdx.x < NG;
    const int r0 = (isG ? blockIdx.x : (blockIdx.x - NG)) * 128;

    if (!isG) {
        if (t < 128) tids[t] = tgt[r0 + t];
        __syncthreads();
    }
    const short* Bf = isG ? M1f : M2f;

    // half 0: load -> stage -> barrier
    Regs8 rg0;
    gt_load(R, tids, isG, r0, V, t, rg0);
    gt_stage(buf[0], t, rg0);
    __syncthreads();

    // issue half-1 loads (fly under half-0 compute)
    Regs8 rg1;
    gt_load(R, tids + 64, isG, r0 + 64, V, t, rg1);

    // compute + store half 0
    gt_compute(buf[0], Bf, Mb, isG, r0, V, w, l, G8, Ttb);

    // stage half 1 -> barrier -> compute
    gt_stage(buf[1], t, rg1);
    __syncthreads();
    gt_compute(buf[1], Bf, Mb, isG, r0 + 64, V, w, l, G8, Ttb);
}

// ---- k_hh: 16 b's/block. h = sum_c relu(G8[ctx] + Ttb) (permuted cols) -> LDS frags -> heads GEMM
__global__ __launch_bounds__(256, 6)
void k_hh(const int* __restrict__ ctx, const unsigned char* __restrict__ G8,
          const short* __restrict__ Ttb, const short* __restrict__ B2f,
          const float* __restrict__ Ub, const float* __restrict__ Wb,
          float* __restrict__ out, int Bsz)
{
    __shared__ __align__(16) short hfr[8 * 64 * 8];   // 8 KB
    __shared__ int ids[16 * C_CTX];
    const int t = threadIdx.x, w = t >> 6, l = t & 63;
    const int b0 = blockIdx.x * 16;

    if (t < 16 * C_CTX) ids[t] = ctx[(size_t)b0 * C_CTX + t];
    __syncthreads();

    const int hw = l >> 5;               // half-wave
    const int i5 = l & 31;
    const int kcc = i5 & 7, sub = i5 >> 3;
    const int c8 = kcc * 32 + sub * 8;   // permuted col base; 32 lanes cover the row

    #pragma unroll
    for (int p = 0; p < 2; ++p) {
        int bl = p * 8 + w * 2 + hw;     // local row 0..15
        short8 tr = *(const short8*)(Ttb + (size_t)(b0 + bl) * E_DIM + c8);
        float tv[8], acc[8];
        #pragma unroll
        for (int j = 0; j < 8; ++j) { tv[j] = bf2f(tr[j]); acc[j] = 0.f; }
        #pragma unroll
        for (int c = 0; c < C_CTX; ++c) {
            uint2 g = *(const uint2*)(G8 + (size_t)ids[bl * C_CTX + c] * E_DIM + c8);
            floatx2 d01 = __builtin_amdgcn_cvt_pk_f32_fp8((int)g.x, false);
            floatx2 d23 = __builtin_amdgcn_cvt_pk_f32_fp8((int)g.x, true);
            floatx2 d45 = __builtin_amdgcn_cvt_pk_f32_fp8((int)g.y, false);
            floatx2 d67 = __builtin_amdgcn_cvt_pk_f32_fp8((int)g.y, true);
            acc[0] += fmaxf(d01[0] + tv[0], 0.f);
            acc[1] += fmaxf(d01[1] + tv[1], 0.f);
            acc[2] += fmaxf(d23[0] + tv[2], 0.f);
            acc[3] += fmaxf(d23[1] + tv[3], 0.f);
            acc[4] += fmaxf(d45[0] + tv[4], 0.f);
            acc[5] += fmaxf(d45[1] + tv[5], 0.f);
            acc[6] += fmaxf(d67[0] + tv[6], 0.f);
            acc[7] += fmaxf(d67[1] + tv[7], 0.f);
        }
        int sp = (sub * 16 + bl) ^ kcc;
        short8 o;
        #pragma unroll
        for (int j = 0; j < 8; ++j) o[j] = f2bf(acc[j]);
        *(short8*)&hfr[(kcc * 64 + sp) * 8] = o;
    }
    __syncthreads();

    // heads GEMM: 16 rows x 256 cols x K=256 (K in permuted order, matching B2f)
    floatx4 acc2[4];
    #pragma unroll
    for (int ni = 0; ni < 4; ++ni)
        acc2[ni] = (floatx4){0.f, 0.f, 0.f, 0.f};

    #pragma unroll
    for (int kc = 0; kc < 8; ++kc) {
        short8 afr = *(const short8*)&hfr[(kc * 64 + (l ^ kc)) * 8];
        short8 bfr[4];
        #pragma unroll
        for (int ni = 0; ni < 4; ++ni)
            bfr[ni] = *(const short8*)(B2f + ((((size_t)w * 8 + kc) * 4 + ni) * 64 + l) * 8);
        #pragma unroll
        for (int ni = 0; ni < 4; ++ni)
            acc2[ni] = __builtin_amdgcn_mfma_f32_16x16x32_bf16(afr, bfr[ni], acc2[ni], 0, 0, 0);
    }

    #pragma unroll
    for (int ni = 0; ni < 4; ++ni) {
        int col = w * 64 + ni * 16 + (l & 15);
        #pragma unroll
        for (int j = 0; j < 4; ++j) {
            int rr = (l >> 4) * 4 + j;   // 0..15
            int r = b0 + rr;
            float v = acc2[ni][j];
            if (col < 128) {
                out[(size_t)r * 128 + col] = v + Ub[col];
            } else {
                float xx = v + Wb[col - 128];
                float sp = fmaxf(xx, 0.f) + log1pf(expf(-fabsf(xx)));
                out[(size_t)Bsz * 128 + (size_t)r * 128 + (col - 128)] = sp;
            }
        }
    }
}

// ==================== launch ====================
extern "C" void kernel_launch(void* const* d_in, const int* in_sizes, int n_in,
                              void* d_out, int out_size, void* d_ws, size_t ws_size,
                              hipStream_t stream)
{
    const int*   tgt = (const int*)d_in[0];
    const int*   ctx = (const int*)d_in[1];
    const float* R   = (const float*)d_in[2];
    const float* Mw  = (const float*)d_in[3];
    const float* Mb  = (const float*)d_in[4];
    const float* Uw  = (const float*)d_in[5];
    const float* Ub  = (const float*)d_in[6];
    const float* Ww  = (const float*)d_in[7];
    const float* Wb  = (const float*)d_in[8];
    float* out = (float*)d_out;
    const int Bsz = in_sizes[0];
    const int Vn  = in_sizes[2] / D_EMB;

    char* ws = (char*)d_ws;
    size_t offG   = 0;                               // V*256 fp8  = 25.6 MB
    size_t offT   = offG + (size_t)Vn * 256;         // B*256 bf16 = 8.4 MB
    size_t offM1f = offT + (size_t)Bsz * 512;
    size_t offM2f = offM1f + 65536;
    size_t offB2f = offM2f + 65536;

    unsigned char* G8 = (unsigned char*)(ws + offG);
    short* Ttb = (short*)(ws + offT);
    short* M1f = (short*)(ws + offM1f);
    short* M2f = (short*)(ws + offM2f);
    short* B2f = (short*)(ws + offB2f);

    const int NG = (Vn + 127) / 128;
    const int NT = Bsz / 128;

    prep_main<<<64, 256, 0, stream>>>(Mw, Uw, Ww, M1f, M2f, B2f);
    k_gt2<<<NG + NT, 256, 0, stream>>>(R, M1f, M2f, Mb, tgt, G8, Ttb, Vn, NG);
    k_hh<<<Bsz / 16, 256, 0, stream>>>(ctx, G8, Ttb, B2f, Ub, Wb, out, Bsz);
}